// Round 5
// baseline (51.605 us; speedup 1.0000x reference)
//
#include <hip/hip_runtime.h>

typedef unsigned short ushort_t;
typedef __bf16 bf16x8 __attribute__((ext_vector_type(8)));
typedef float f32x4 __attribute__((ext_vector_type(4)));

#define AS1 __attribute__((address_space(1)))
#define AS3 __attribute__((address_space(3)))

__device__ __forceinline__ ushort_t f2bf(float f) {
    unsigned u = __builtin_bit_cast(unsigned, f);
    u = (u + 0x7fffu + ((u >> 16) & 1u)) >> 16;
    return (ushort_t)u;
}

__device__ __forceinline__ void async16(void* lds, const void* g) {
    __builtin_amdgcn_global_load_lds((const AS1 unsigned int*)g,
                                     (AS3 unsigned int*)lds, 16, 0, 0);
}

__device__ __forceinline__ void softmax2(const float* __restrict__ sig, float& s0, float& s1) {
    float a = sig[0], b = sig[1];
    float m = fmaxf(a, b);
    float e0 = __expf(a - m), e1 = __expf(b - m);
    float inv = 1.0f / (e0 + e1);
    s0 = e0 * inv; s1 = e1 * inv;
}

// toeplitz value: W_toep[k][o]
__device__ __forceinline__ float toep_val(const float* __restrict__ Wseed, int k, int o) {
    return (k >= o) ? Wseed[(size_t)(k - o) << 10] : Wseed[o - k];
}

// ---------------- prep: W_core^T bf16 only (x is consumed fp32 by the GEMM now) ----
// 256 blocks, each a 64x64 (k,o) tile: read Wseed rows coalesced, transpose via LDS,
// write Wt[o][k] bf16 coalesced.
__global__ __launch_bounds__(256) void prep_w_kernel(const float* __restrict__ Wseed,
                                                     const float* __restrict__ Wsig,
                                                     ushort_t* __restrict__ Wt) {
    __shared__ float T[64][65];                 // [k-within][o-within], padded
    int bb = blockIdx.x;                        // 0..255
    int k0 = (bb >> 4) * 64;
    int o0 = (bb & 15) * 64;
    int t = threadIdx.x;
    #pragma unroll
    for (int i = 0; i < 4; ++i) {
        int lin = t + i * 256;                  // 0..1023
        int kr = lin >> 4;                      // 0..63
        int c4 = lin & 15;                      // 0..15
        float4 v = *(const float4*)&Wseed[(size_t)(k0 + kr) * 1024 + o0 + c4 * 4];
        T[kr][c4 * 4 + 0] = v.x;
        T[kr][c4 * 4 + 1] = v.y;
        T[kr][c4 * 4 + 2] = v.z;
        T[kr][c4 * 4 + 3] = v.w;
    }
    __syncthreads();
    float s0, s1; softmax2(Wsig, s0, s1);
    #pragma unroll
    for (int i = 0; i < 2; ++i) {
        int lin = t + i * 256;                  // 0..511
        int oo = lin >> 3;                      // 0..63
        int kq = (lin & 7) * 8;                 // 0,8,..,56
        unsigned r[4];
        #pragma unroll
        for (int q = 0; q < 4; ++q) {
            float v0 = s0 * T[kq + 2 * q + 0][oo] + s1 * toep_val(Wseed, k0 + kq + 2 * q + 0, o0 + oo);
            float v1 = s0 * T[kq + 2 * q + 1][oo] + s1 * toep_val(Wseed, k0 + kq + 2 * q + 1, o0 + oo);
            r[q] = (unsigned)f2bf(v0) | ((unsigned)f2bf(v1) << 16);
        }
        *(uint4*)&Wt[(size_t)(o0 + oo) * 1024 + k0 + kq] = make_uint4(r[0], r[1], r[2], r[3]);
    }
}

// ---------------- main GEMM: C = x(fp32) @ Wt^T, fused bias + activation mixture ----
// 128x128 tile, BK=32, grid 512, double-buffered LDS, one barrier per K-step.
// A is reg-staged straight from fp32 x (T14 issue-early / cvt+ds_write-late):
// global float4 loads issued BEFORE compute, converted to bf16 and written to the
// next LDS buffer AFTER compute. B stays on the global_load_lds path from Wt.
#define BM 128
#define BN 128
#define BK 32
#define NKT 32   // 1024 / 32

__global__ __launch_bounds__(256, 2) void gemm_kernel(const float* __restrict__ Xf,
                                                      const ushort_t* __restrict__ Wt,
                                                      const float* __restrict__ bseed,
                                                      const float* __restrict__ bsig,
                                                      const float* __restrict__ asig,
                                                      float* __restrict__ out) {
    // double buffer: [buf][A(4096) | B(4096)] ushorts = 32 KB total
    __shared__ ushort_t lds[16384];
    ushort_t* At0 = lds;
    ushort_t* Bt0 = lds + 4096;
    ushort_t* At1 = lds + 8192;
    ushort_t* Bt1 = lds + 12288;

    const int t = threadIdx.x;        // 0..255
    const int wv = t >> 6;
    const int lane = t & 63;

    // XCD-aware swizzle (512 blocks, 512%8==0 -> bijective)
    const int orig = blockIdx.x;
    const int g = orig & 7;           // XCD id under round-robin dispatch
    const int within = orig >> 3;     // 0..63 within this XCD
    const int rb = g * 8 + (within >> 3);   // row-block 0..63 (8 per XCD)
    const int cb = within & 7;              // col-block 0..7
    const int brow = rb * BM;
    const int bcol = cb * BN;

    // staging: thread t covers 8 contiguous elements; 4 threads per 32-elem row
    const int r0 = t >> 2;            // 0..63
    const int kc = (t & 3) * 8;       // 0,8,16,24
    const float* gX0 = Xf + (size_t)(brow + r0) * 1024 + kc;        // A rows 0..63 (fp32)
    const float* gX1 = Xf + (size_t)(brow + 64 + r0) * 1024 + kc;   // A rows 64..127
    const ushort_t* gB0 = Wt + (size_t)(bcol + r0) * 1024 + kc;
    const ushort_t* gB1 = Wt + (size_t)(bcol + 64 + r0) * 1024 + kc;

    f32x4 acc[4][4];
    #pragma unroll
    for (int i = 0; i < 4; ++i)
        #pragma unroll
        for (int j = 0; j < 4; ++j) acc[i][j] = (f32x4){0.f, 0.f, 0.f, 0.f};

    const int wr = (wv >> 1) * 64;    // wave row origin in tile
    const int wcn = (wv & 1) * 64;    // wave col origin in tile
    const int fr = lane & 15;         // fragment row/col within 16
    const int kg = (lane >> 4) * 8;   // k-group offset

    // wave-uniform LDS staging bases for B (lane*16B implicit in global_load_lds)
    const int sA = wv * 512;
    const int sA2 = 2048 + wv * 512;
    // A reg-staging registers (constant-indexed only — rule #20)
    f32x4 ar0, ar1, ar2, ar3;

#define LOADA(ko)                                          \
    do {                                                   \
        ar0 = *(const f32x4*)(gX0 + (ko));                 \
        ar1 = *(const f32x4*)(gX0 + (ko) + 4);             \
        ar2 = *(const f32x4*)(gX1 + (ko));                 \
        ar3 = *(const f32x4*)(gX1 + (ko) + 4);             \
    } while (0)

// thread t's 16B lands at linear ushort offset t*8 (== row r0 * 32 + kc), matching
// the B-path layout verified in earlier rounds.
#define WRITEA(Abuf)                                       \
    do {                                                   \
        bf16x8 v0, v1;                                     \
        _Pragma("unroll")                                  \
        for (int j = 0; j < 4; ++j) {                      \
            v0[j]     = (__bf16)ar0[j];                    \
            v0[4 + j] = (__bf16)ar1[j];                    \
            v1[j]     = (__bf16)ar2[j];                    \
            v1[4 + j] = (__bf16)ar3[j];                    \
        }                                                  \
        *(bf16x8*)&(Abuf)[t * 8] = v0;                     \
        *(bf16x8*)&(Abuf)[2048 + t * 8] = v1;              \
    } while (0)

#define STAGEB(Bbuf, ko)                                   \
    do {                                                   \
        async16((Bbuf) + sA,  gB0 + (ko));                 \
        async16((Bbuf) + sA2, gB1 + (ko));                 \
    } while (0)

#define COMPUTE(Abuf, Bbuf)                                                        \
    do {                                                                           \
        bf16x8 af[4], bf[4];                                                       \
        _Pragma("unroll")                                                          \
        for (int mi = 0; mi < 4; ++mi)                                             \
            af[mi] = *(const bf16x8*)&(Abuf)[(wr + mi * 16 + fr) * BK + kg];       \
        _Pragma("unroll")                                                          \
        for (int ni = 0; ni < 4; ++ni)                                             \
            bf[ni] = *(const bf16x8*)&(Bbuf)[(wcn + ni * 16 + fr) * BK + kg];      \
        _Pragma("unroll")                                                          \
        for (int mi = 0; mi < 4; ++mi)                                             \
            _Pragma("unroll")                                                      \
            for (int ni = 0; ni < 4; ++ni)                                         \
                acc[mi][ni] = __builtin_amdgcn_mfma_f32_16x16x32_bf16(             \
                    af[mi], bf[ni], acc[mi][ni], 0, 0, 0);                         \
    } while (0)

    // prologue: stage K-step 0 into buf0
    LOADA(0);
    STAGEB(Bt0, 0);
    WRITEA(At0);
    __syncthreads();
    // main: 15 double-iterations, static buffer names
    for (int it = 0; it < 15; ++it) {
        LOADA((2 * it + 1) * BK);             // issue A loads early (latency under MFMA)
        STAGEB(Bt1, (2 * it + 1) * BK);
        COMPUTE(At0, Bt0);
        WRITEA(At1);                          // cvt+write late; buf1's last reader synced
        __syncthreads();
        LOADA((2 * it + 2) * BK);
        STAGEB(Bt0, (2 * it + 2) * BK);
        COMPUTE(At1, Bt1);
        WRITEA(At0);
        __syncthreads();
    }
    // tail: K-steps 30, 31
    LOADA(31 * BK);
    STAGEB(Bt1, 31 * BK);
    COMPUTE(At0, Bt0);
    WRITEA(At1);
    __syncthreads();
    COMPUTE(At1, Bt1);

    // epilogue: bias + activation mixture
    float bs0, bs1, as0, as1;
    softmax2(bsig, bs0, bs1);
    softmax2(asig, as0, as1);

    #pragma unroll
    for (int ni = 0; ni < 4; ++ni) {
        int col = bcol + wcn + ni * 16 + fr;
        float bias = bs0 * bseed[col];
        #pragma unroll
        for (int mi = 0; mi < 4; ++mi) {
            int row = brow + wr + mi * 16 + (lane >> 4) * 4;
            #pragma unroll
            for (int r = 0; r < 4; ++r) {
                float v = acc[mi][ni][r] + bias;
                out[(size_t)(row + r) * 1024 + col] = as0 * v + as1 * fmaxf(v, 0.f);
            }
        }
    }
#undef LOADA
#undef WRITEA
#undef STAGEB
#undef COMPUTE
}

// ---------------- fallback (only if workspace too small): naive fp32 ----------------
__global__ __launch_bounds__(256) void naive_kernel(const float* __restrict__ x,
                                                    const float* __restrict__ Wseed,
                                                    const float* __restrict__ bseed,
                                                    const float* __restrict__ Wsig,
                                                    const float* __restrict__ bsig,
                                                    const float* __restrict__ asig,
                                                    float* __restrict__ out) {
    int idx = blockIdx.x * 256 + threadIdx.x;
    int b = idx >> 10, o = idx & 1023;
    float ws0, ws1, bs0, bs1, as0, as1;
    softmax2(Wsig, ws0, ws1);
    softmax2(bsig, bs0, bs1);
    softmax2(asig, as0, as1);
    float s = 0.f;
    const float* xr = x + (size_t)b * 1024;
    for (int k = 0; k < 1024; ++k) {
        float wc = ws0 * Wseed[((size_t)k << 10) + o] + ws1 * toep_val(Wseed, k, o);
        s += xr[k] * wc;
    }
    float v = s + bs0 * bseed[o];
    out[idx] = as0 * v + as1 * fmaxf(v, 0.f);
}

extern "C" void kernel_launch(void* const* d_in, const int* in_sizes, int n_in,
                              void* d_out, int out_size, void* d_ws, size_t ws_size,
                              hipStream_t stream) {
    const float* x     = (const float*)d_in[0];
    const float* Wseed = (const float*)d_in[1];
    const float* bseed = (const float*)d_in[2];
    const float* Wsig  = (const float*)d_in[3];
    const float* bsig  = (const float*)d_in[4];
    const float* Asig  = (const float*)d_in[5];
    float* out = (float*)d_out;

    const size_t need = (2u << 20) + 1024;
    if (ws_size < need) {
        naive_kernel<<<dim3(8192 * 1024 / 256), dim3(256), 0, stream>>>(
            x, Wseed, bseed, Wsig, bsig, Asig, out);
        return;
    }

    ushort_t* Wt = (ushort_t*)d_ws;   // 2 MB: W_core^T bf16 [1024][1024]

    prep_w_kernel<<<dim3(256), dim3(256), 0, stream>>>(Wseed, Wsig, Wt);
    gemm_kernel<<<dim3(512), dim3(256), 0, stream>>>(x, Wt, bseed, bsig, Asig, out);
}

// Round 6
// 43.105 us; speedup vs baseline: 1.1972x; 1.1972x over previous
//
#include <hip/hip_runtime.h>

typedef unsigned short ushort_t;
typedef __bf16 bf16x8 __attribute__((ext_vector_type(8)));
typedef float f32x4 __attribute__((ext_vector_type(4)));

#define AS1 __attribute__((address_space(1)))
#define AS3 __attribute__((address_space(3)))

__device__ __forceinline__ ushort_t f2bf(float f) {
    unsigned u = __builtin_bit_cast(unsigned, f);
    u = (u + 0x7fffu + ((u >> 16) & 1u)) >> 16;
    return (ushort_t)u;
}

__device__ __forceinline__ void async16(void* lds, const void* g) {
    __builtin_amdgcn_global_load_lds((const AS1 unsigned int*)g,
                                     (AS3 unsigned int*)lds, 16, 0, 0);
}

__device__ __forceinline__ void softmax2(const float* __restrict__ sig, float& s0, float& s1) {
    float a = sig[0], b = sig[1];
    float m = fmaxf(a, b);
    float e0 = __expf(a - m), e1 = __expf(b - m);
    float inv = 1.0f / (e0 + e1);
    s0 = e0 * inv; s1 = e1 * inv;
}

// toeplitz value: W_toep[k][o]
__device__ __forceinline__ float toep_val(const float* __restrict__ Wseed, int k, int o) {
    return (k >= o) ? Wseed[(size_t)(k - o) << 10] : Wseed[o - k];
}

// ---------------- merged prep (R4-verified) ----------------
// blocks [0, 4096):    x fp32 [8192][1024] -> xb bf16, 8 elems/thread (coalesced)
// blocks [4096, 4352): 256 blocks, each a 64x64 (k,o) tile of W:
//   read Wseed rows coalesced, transpose via LDS, write Wt[o][k] bf16 coalesced.
__global__ __launch_bounds__(256) void prep_kernel(const float* __restrict__ x,
                                                   const float* __restrict__ Wseed,
                                                   const float* __restrict__ Wsig,
                                                   ushort_t* __restrict__ xb,
                                                   ushort_t* __restrict__ Wt) {
    int b = blockIdx.x;
    if (b < 4096) {
        int i = b * 256 + threadIdx.x;          // 1M threads, 8 elems each
        const float4* xp = (const float4*)x + (size_t)i * 2;
        float4 a = xp[0], c = xp[1];
        uint4 r;
        r.x = (unsigned)f2bf(a.x) | ((unsigned)f2bf(a.y) << 16);
        r.y = (unsigned)f2bf(a.z) | ((unsigned)f2bf(a.w) << 16);
        r.z = (unsigned)f2bf(c.x) | ((unsigned)f2bf(c.y) << 16);
        r.w = (unsigned)f2bf(c.z) | ((unsigned)f2bf(c.w) << 16);
        ((uint4*)xb)[i] = r;
        return;
    }
    // ---- W transpose tile ----
    __shared__ float T[64][65];                 // [k-within][o-within], padded
    int bb = b - 4096;                          // 0..255
    int k0 = (bb >> 4) * 64;
    int o0 = (bb & 15) * 64;
    int t = threadIdx.x;
    #pragma unroll
    for (int i = 0; i < 4; ++i) {
        int lin = t + i * 256;                  // 0..1023
        int kr = lin >> 4;                      // 0..63
        int c4 = lin & 15;                      // 0..15
        float4 v = *(const float4*)&Wseed[(size_t)(k0 + kr) * 1024 + o0 + c4 * 4];
        T[kr][c4 * 4 + 0] = v.x;
        T[kr][c4 * 4 + 1] = v.y;
        T[kr][c4 * 4 + 2] = v.z;
        T[kr][c4 * 4 + 3] = v.w;
    }
    __syncthreads();
    float s0, s1; softmax2(Wsig, s0, s1);
    #pragma unroll
    for (int i = 0; i < 2; ++i) {
        int lin = t + i * 256;                  // 0..511
        int oo = lin >> 3;                      // 0..63
        int kq = (lin & 7) * 8;                 // 0,8,..,56
        unsigned r[4];
        #pragma unroll
        for (int q = 0; q < 4; ++q) {
            float v0 = s0 * T[kq + 2 * q + 0][oo] + s1 * toep_val(Wseed, k0 + kq + 2 * q + 0, o0 + oo);
            float v1 = s0 * T[kq + 2 * q + 1][oo] + s1 * toep_val(Wseed, k0 + kq + 2 * q + 1, o0 + oo);
            r[q] = (unsigned)f2bf(v0) | ((unsigned)f2bf(v1) << 16);
        }
        *(uint4*)&Wt[(size_t)(o0 + oo) * 1024 + k0 + kq] = make_uint4(r[0], r[1], r[2], r[3]);
    }
}

// ---------------- main GEMM: C = Xb @ Wt^T, fused bias + activation mixture ----------------
// 128x128 tile, BK=32, grid 512, double-buffered LDS.
// T4 sync: counted `s_waitcnt vmcnt(4)` + raw s_barrier — next-tile global_load_lds
// stay in flight across barriers (no vmcnt(0) drain in the main loop).
// Race ledger:
//  - STAGE(bufX) overwrite: protected by the barrier AFTER COMPUTE(bufX) (all waves'
//    ds_reads feed MFMAs -> complete before that barrier).
//  - COMPUTE(bufX) read: per-wave vmcnt(4) retires the 4 oldest loads (= bufX's),
//    then s_barrier makes every wave's bufX writes visible.
//  - vmcnt count integrity: all other vmem (epilogue scalars) is loaded, consumed and
//    pinned BEFORE the prologue STAGE.
#define BM 128
#define BN 128
#define BK 32
#define NKT 32   // 1024 / 32

__global__ __launch_bounds__(256, 2) void gemm_kernel(const ushort_t* __restrict__ Xb,
                                                      const ushort_t* __restrict__ Wt,
                                                      const float* __restrict__ bseed,
                                                      const float* __restrict__ bsig,
                                                      const float* __restrict__ asig,
                                                      float* __restrict__ out) {
    // double buffer: [buf][A(4096) | B(4096)] ushorts = 32 KB total
    __shared__ ushort_t lds[16384];
    ushort_t* At0 = lds;
    ushort_t* Bt0 = lds + 4096;
    ushort_t* At1 = lds + 8192;
    ushort_t* Bt1 = lds + 12288;

    const int t = threadIdx.x;        // 0..255
    const int wv = t >> 6;
    const int lane = t & 63;

    // XCD-aware swizzle (512 blocks, 512%8==0 -> bijective)
    const int orig = blockIdx.x;
    const int g = orig & 7;           // XCD id under round-robin dispatch
    const int within = orig >> 3;     // 0..63 within this XCD
    const int rb = g * 8 + (within >> 3);   // row-block 0..63 (8 per XCD)
    const int cb = within & 7;              // col-block 0..7
    const int brow = rb * BM;
    const int bcol = cb * BN;

    // staging: thread t covers 8 contiguous bf16 (16B); 4 threads per 32-elem row
    const int r0 = t >> 2;            // 0..63
    const int kc = (t & 3) * 8;       // 0,8,16,24
    const ushort_t* gA0 = Xb + (size_t)(brow + r0) * 1024 + kc;
    const ushort_t* gA1 = Xb + (size_t)(brow + 64 + r0) * 1024 + kc;
    const ushort_t* gB0 = Wt + (size_t)(bcol + r0) * 1024 + kc;
    const ushort_t* gB1 = Wt + (size_t)(bcol + 64 + r0) * 1024 + kc;

    f32x4 acc[4][4];
    #pragma unroll
    for (int i = 0; i < 4; ++i)
        #pragma unroll
        for (int j = 0; j < 4; ++j) acc[i][j] = (f32x4){0.f, 0.f, 0.f, 0.f};

    const int wr = (wv >> 1) * 64;    // wave row origin in tile
    const int wcn = (wv & 1) * 64;    // wave col origin in tile
    const int fr = lane & 15;         // fragment row/col within 16
    const int kg = (lane >> 4) * 8;   // k-group offset

    // ---- epilogue scalars: load, consume, and pin BEFORE any staging so no stray
    // vmem op is outstanding during the counted-vmcnt loop ----
    float bs0, bs1, as0, as1;
    softmax2(bsig, bs0, bs1);
    softmax2(asig, as0, as1);
    float bias[4];
    #pragma unroll
    for (int ni = 0; ni < 4; ++ni)
        bias[ni] = bs0 * bseed[bcol + wcn + ni * 16 + fr];
    asm volatile("" :: "v"(bias[0]), "v"(bias[1]), "v"(bias[2]), "v"(bias[3]),
                       "v"(as0), "v"(as1));
    asm volatile("" ::: "memory");

    // wave-uniform LDS staging bases (lane*16B implicit in global_load_lds)
    const int sA = wv * 512;
    const int sA2 = 2048 + wv * 512;
#define STAGE(Abuf, Bbuf, ko)                                  \
    do {                                                       \
        async16((Abuf) + sA,  gA0 + (ko));                     \
        async16((Abuf) + sA2, gA1 + (ko));                     \
        async16((Bbuf) + sA,  gB0 + (ko));                     \
        async16((Bbuf) + sA2, gB1 + (ko));                     \
    } while (0)

#define COMPUTE(Abuf, Bbuf)                                                        \
    do {                                                                           \
        bf16x8 af[4], bf[4];                                                       \
        _Pragma("unroll")                                                          \
        for (int mi = 0; mi < 4; ++mi)                                             \
            af[mi] = *(const bf16x8*)&(Abuf)[(wr + mi * 16 + fr) * BK + kg];       \
        _Pragma("unroll")                                                          \
        for (int ni = 0; ni < 4; ++ni)                                             \
            bf[ni] = *(const bf16x8*)&(Bbuf)[(wcn + ni * 16 + fr) * BK + kg];      \
        _Pragma("unroll")                                                          \
        for (int mi = 0; mi < 4; ++mi)                                             \
            _Pragma("unroll")                                                      \
            for (int ni = 0; ni < 4; ++ni)                                         \
                acc[mi][ni] = __builtin_amdgcn_mfma_f32_16x16x32_bf16(             \
                    af[mi], bf[ni], acc[mi][ni], 0, 0, 0);                         \
    } while (0)

#define WAIT4() asm volatile("s_waitcnt vmcnt(4)" ::: "memory")
#define WAIT0() asm volatile("s_waitcnt vmcnt(0)" ::: "memory")
#define BAR()   __builtin_amdgcn_s_barrier()
#define PIN()   __builtin_amdgcn_sched_barrier(0)

    // prologue
    STAGE(At0, Bt0, 0);
    // main: 15 double-iterations, static buffer names
    for (int it = 0; it < 15; ++it) {
        STAGE(At1, Bt1, (2 * it + 1) * BK);   // 4 loads in flight across barriers
        WAIT4(); BAR(); PIN();                // buf0 ready (everyone)
        COMPUTE(At0, Bt0);
        BAR();                                // everyone done reading buf0
        STAGE(At0, Bt0, (2 * it + 2) * BK);
        WAIT4(); BAR(); PIN();                // buf1 ready
        COMPUTE(At1, Bt1);
        BAR();                                // everyone done reading buf1
    }
    // tail: K-steps 30, 31
    STAGE(At1, Bt1, 31 * BK);
    WAIT4(); BAR(); PIN();
    COMPUTE(At0, Bt0);
    WAIT0(); BAR(); PIN();                    // buf1 fully staged; no overwrite follows
    COMPUTE(At1, Bt1);

    // epilogue: bias + activation mixture (scalars precomputed above)
    #pragma unroll
    for (int ni = 0; ni < 4; ++ni) {
        int col = bcol + wcn + ni * 16 + fr;
        #pragma unroll
        for (int mi = 0; mi < 4; ++mi) {
            int row = brow + wr + mi * 16 + (lane >> 4) * 4;
            #pragma unroll
            for (int r = 0; r < 4; ++r) {
                float v = acc[mi][ni][r] + bias[ni];
                out[(size_t)(row + r) * 1024 + col] = as0 * v + as1 * fmaxf(v, 0.f);
            }
        }
    }
#undef STAGE
#undef COMPUTE
#undef WAIT4
#undef WAIT0
#undef BAR
#undef PIN
}

// ---------------- fallback (only if workspace too small): naive fp32 ----------------
__global__ __launch_bounds__(256) void naive_kernel(const float* __restrict__ x,
                                                    const float* __restrict__ Wseed,
                                                    const float* __restrict__ bseed,
                                                    const float* __restrict__ Wsig,
                                                    const float* __restrict__ bsig,
                                                    const float* __restrict__ asig,
                                                    float* __restrict__ out) {
    int idx = blockIdx.x * 256 + threadIdx.x;
    int b = idx >> 10, o = idx & 1023;
    float ws0, ws1, bs0, bs1, as0, as1;
    softmax2(Wsig, ws0, ws1);
    softmax2(bsig, bs0, bs1);
    softmax2(asig, as0, as1);
    float s = 0.f;
    const float* xr = x + (size_t)b * 1024;
    for (int k = 0; k < 1024; ++k) {
        float wc = ws0 * Wseed[((size_t)k << 10) + o] + ws1 * toep_val(Wseed, k, o);
        s += xr[k] * wc;
    }
    float v = s + bs0 * bseed[o];
    out[idx] = as0 * v + as1 * fmaxf(v, 0.f);
}

extern "C" void kernel_launch(void* const* d_in, const int* in_sizes, int n_in,
                              void* d_out, int out_size, void* d_ws, size_t ws_size,
                              hipStream_t stream) {
    const float* x     = (const float*)d_in[0];
    const float* Wseed = (const float*)d_in[1];
    const float* bseed = (const float*)d_in[2];
    const float* Wsig  = (const float*)d_in[3];
    const float* bsig  = (const float*)d_in[4];
    const float* Asig  = (const float*)d_in[5];
    float* out = (float*)d_out;

    const size_t need = (2u << 20) + (16u << 20) + 1024;
    if (ws_size < need) {
        naive_kernel<<<dim3(8192 * 1024 / 256), dim3(256), 0, stream>>>(
            x, Wseed, bseed, Wsig, bsig, Asig, out);
        return;
    }

    ushort_t* Wt = (ushort_t*)d_ws;                         // 2 MB: W_core^T bf16 [1024][1024]
    ushort_t* Xb = (ushort_t*)((char*)d_ws + (2u << 20));   // 16 MB: x bf16 [8192][1024]

    prep_kernel<<<dim3(4096 + 256), dim3(256), 0, stream>>>(x, Wseed, Wsig, Xb, Wt);
    gemm_kernel<<<dim3(512), dim3(256), 0, stream>>>(Xb, Wt, bseed, bsig, Asig, out);
}

// Round 7
// 42.978 us; speedup vs baseline: 1.2007x; 1.0030x over previous
//
#include <hip/hip_runtime.h>

typedef unsigned short ushort_t;
typedef __bf16 bf16x8 __attribute__((ext_vector_type(8)));
typedef float f32x4 __attribute__((ext_vector_type(4)));

#define AS1 __attribute__((address_space(1)))
#define AS3 __attribute__((address_space(3)))

__device__ __forceinline__ ushort_t f2bf(float f) {
    unsigned u = __builtin_bit_cast(unsigned, f);
    u = (u + 0x7fffu + ((u >> 16) & 1u)) >> 16;
    return (ushort_t)u;
}

__device__ __forceinline__ void async16(void* lds, const void* g) {
    __builtin_amdgcn_global_load_lds((const AS1 unsigned int*)g,
                                     (AS3 unsigned int*)lds, 16, 0, 0);
}

__device__ __forceinline__ void softmax2(const float* __restrict__ sig, float& s0, float& s1) {
    float a = sig[0], b = sig[1];
    float m = fmaxf(a, b);
    float e0 = __expf(a - m), e1 = __expf(b - m);
    float inv = 1.0f / (e0 + e1);
    s0 = e0 * inv; s1 = e1 * inv;
}

// toeplitz value: W_toep[k][o]
__device__ __forceinline__ float toep_val(const float* __restrict__ Wseed, int k, int o) {
    return (k >= o) ? Wseed[(size_t)(k - o) << 10] : Wseed[o - k];
}

// ---------------- merged prep (R4-verified) ----------------
// blocks [0, 4096):    x fp32 [8192][1024] -> xb bf16, 8 elems/thread (coalesced)
// blocks [4096, 4352): 256 blocks, each a 64x64 (k,o) tile of W:
//   read Wseed rows coalesced, transpose via LDS, write Wt[o][k] bf16 coalesced.
__global__ __launch_bounds__(256) void prep_kernel(const float* __restrict__ x,
                                                   const float* __restrict__ Wseed,
                                                   const float* __restrict__ Wsig,
                                                   ushort_t* __restrict__ xb,
                                                   ushort_t* __restrict__ Wt) {
    int b = blockIdx.x;
    if (b < 4096) {
        int i = b * 256 + threadIdx.x;          // 1M threads, 8 elems each
        const float4* xp = (const float4*)x + (size_t)i * 2;
        float4 a = xp[0], c = xp[1];
        uint4 r;
        r.x = (unsigned)f2bf(a.x) | ((unsigned)f2bf(a.y) << 16);
        r.y = (unsigned)f2bf(a.z) | ((unsigned)f2bf(a.w) << 16);
        r.z = (unsigned)f2bf(c.x) | ((unsigned)f2bf(c.y) << 16);
        r.w = (unsigned)f2bf(c.z) | ((unsigned)f2bf(c.w) << 16);
        ((uint4*)xb)[i] = r;
        return;
    }
    __shared__ float T[64][65];                 // [k-within][o-within], padded
    int bb = b - 4096;                          // 0..255
    int k0 = (bb >> 4) * 64;
    int o0 = (bb & 15) * 64;
    int t = threadIdx.x;
    #pragma unroll
    for (int i = 0; i < 4; ++i) {
        int lin = t + i * 256;
        int kr = lin >> 4;
        int c4 = lin & 15;
        float4 v = *(const float4*)&Wseed[(size_t)(k0 + kr) * 1024 + o0 + c4 * 4];
        T[kr][c4 * 4 + 0] = v.x;
        T[kr][c4 * 4 + 1] = v.y;
        T[kr][c4 * 4 + 2] = v.z;
        T[kr][c4 * 4 + 3] = v.w;
    }
    __syncthreads();
    float s0, s1; softmax2(Wsig, s0, s1);
    #pragma unroll
    for (int i = 0; i < 2; ++i) {
        int lin = t + i * 256;
        int oo = lin >> 3;
        int kq = (lin & 7) * 8;
        unsigned r[4];
        #pragma unroll
        for (int q = 0; q < 4; ++q) {
            float v0 = s0 * T[kq + 2 * q + 0][oo] + s1 * toep_val(Wseed, k0 + kq + 2 * q + 0, o0 + oo);
            float v1 = s0 * T[kq + 2 * q + 1][oo] + s1 * toep_val(Wseed, k0 + kq + 2 * q + 1, o0 + oo);
            r[q] = (unsigned)f2bf(v0) | ((unsigned)f2bf(v1) << 16);
        }
        *(uint4*)&Wt[(size_t)(o0 + oo) * 1024 + k0 + kq] = make_uint4(r[0], r[1], r[2], r[3]);
    }
}

// ---------------- main GEMM: 8-phase schedule (T2+T3+T4+T5) ----------------
// BM=256, BN=128, BK=64, 512 threads = 8 waves (4M x 2N), per-wave 64x64 out.
// grid 256 = 1 block/CU. LDS 96 KB: dbuf x (A 32KB + B 16KB).
// Per K-tile: 4 phases, each {ds_read frag subtile || 2 gloads of tile t+1 ||
// barrier || setprio(1) 8 MFMA setprio(0) || barrier}; vmcnt(0) folded into
// phase 3's trailing barrier only (never drains mid-tile).
// T2 swizzle per rule #21: gload dest LINEAR, global SOURCE column pre-XOR'd
// (kcs), ds_read address XOR'd with ((row&7)<<3) -> 2-way banks (free).
// Race ledger:
//  - overwrite of buf[other] by tile t+1 gloads: last reader was tile t-1,
//    whose ds_reads retired (dataflow lgkm before its MFMAs) before its
//    phase-3 trailing barrier; gloads issue after that barrier.
//  - reads of buf[cur]: staged during tile t-1's phases; per-wave vmcnt(0)
//    then s_barrier at t-1's phase-3 end make all writes visible.
//  - vmcnt integrity: bias/sig loads consumed+pinned BEFORE prologue staging.
#define NKT 16   // 1024 / 64

__global__ __launch_bounds__(512, 2) void gemm_kernel(const ushort_t* __restrict__ Xb,
                                                      const ushort_t* __restrict__ Wt,
                                                      const float* __restrict__ bseed,
                                                      const float* __restrict__ bsig,
                                                      const float* __restrict__ asig,
                                                      float* __restrict__ out) {
    __shared__ ushort_t lds[49152];   // 96 KB
    ushort_t* const A0v = lds;               // 256x64 bf16 (16384)
    ushort_t* const B0v = lds + 16384;       // 128x64 bf16 (8192)
    ushort_t* const A1v = lds + 24576;
    ushort_t* const B1v = lds + 40960;

    const int t = threadIdx.x;        // 0..511
    const int wv = t >> 6;            // 0..7
    const int lane = t & 63;

    // XCD-aware swizzle (256 blocks, 256%8==0 -> bijective); per-XCD set:
    // Xb panel (4 row-blocks x 256 rows x 2KB = 2MB) + full Wt (2MB) = 4MB L2.
    const int orig = blockIdx.x;
    const int g = orig & 7;
    const int within = orig >> 3;           // 0..31
    const int rb = g * 4 + (within >> 3);   // 0..31
    const int cb = within & 7;              // 0..7
    const int brow = rb * 256;
    const int bcol = cb * 128;

    // staging map: 512 threads x 16B = 8KB = 64 rows x 64k x 2B per gload
    const int r0 = t >> 3;                  // 0..63
    const int kcs = 8 * ((t & 7) ^ (r0 & 7));   // inverse-swizzled source column
    const ushort_t* gA = Xb + (size_t)(brow + r0) * 1024 + kcs;
    const ushort_t* gB = Wt + (size_t)(bcol + r0) * 1024 + kcs;

    // fragment geometry
    const int wr = (wv >> 1) * 64;    // wave M origin (0,64,128,192)
    const int wcn = (wv & 1) * 64;    // wave N origin (0,64)
    const int fr = lane & 15;
    const int kg = (lane >> 4) * 8;
    const int frx = (fr & 7) << 3;    // ds_read XOR (ushort units)

    f32x4 acc[4][4];
    #pragma unroll
    for (int i = 0; i < 4; ++i)
        #pragma unroll
        for (int j = 0; j < 4; ++j) acc[i][j] = (f32x4){0.f, 0.f, 0.f, 0.f};
    bf16x8 bfr[4][2];

    // ---- epilogue scalars first: consume + pin so vmcnt stays clean ----
    float bs0, bs1, as0, as1;
    softmax2(bsig, bs0, bs1);
    softmax2(asig, as0, as1);
    float bias[4];
    #pragma unroll
    for (int ni = 0; ni < 4; ++ni)
        bias[ni] = bs0 * bseed[bcol + wcn + ni * 16 + fr];
    asm volatile("" :: "v"(bias[0]), "v"(bias[1]), "v"(bias[2]), "v"(bias[3]),
                       "v"(as0), "v"(as1));
    asm volatile("" ::: "memory");

#define PHASE(p, Abuf, Bbuf, STAGEBLOCK)                                           \
    do {                                                                           \
        const int arow_ = wr + (p) * 16 + fr;                                      \
        bf16x8 a0 = *(const bf16x8*)&(Abuf)[arow_ * 64 + ((0 + kg) ^ frx)];        \
        bf16x8 a1 = *(const bf16x8*)&(Abuf)[arow_ * 64 + ((32 + kg) ^ frx)];       \
        if ((p) == 0) {                                                            \
            _Pragma("unroll")                                                      \
            for (int ni = 0; ni < 4; ++ni) {                                       \
                int brow_ = wcn + ni * 16 + fr;                                    \
                bfr[ni][0] = *(const bf16x8*)&(Bbuf)[brow_ * 64 + ((0 + kg) ^ frx)];  \
                bfr[ni][1] = *(const bf16x8*)&(Bbuf)[brow_ * 64 + ((32 + kg) ^ frx)]; \
            }                                                                      \
        }                                                                          \
        STAGEBLOCK                                                                 \
        asm volatile("" ::: "memory");                                             \
        __builtin_amdgcn_s_barrier();                                              \
        __builtin_amdgcn_s_setprio(1);                                             \
        _Pragma("unroll")                                                          \
        for (int ni = 0; ni < 4; ++ni) {                                           \
            acc[p][ni] = __builtin_amdgcn_mfma_f32_16x16x32_bf16(a0, bfr[ni][0],   \
                                                                 acc[p][ni], 0, 0, 0); \
            acc[p][ni] = __builtin_amdgcn_mfma_f32_16x16x32_bf16(a1, bfr[ni][1],   \
                                                                 acc[p][ni], 0, 0, 0); \
        }                                                                          \
        __builtin_amdgcn_s_setprio(0);                                             \
        asm volatile("" ::: "memory");                                             \
    } while (0)

#define KTILE(Acur, Bcur, Aoth, Both, kt1, DOSTAGE)                                \
    do {                                                                           \
        PHASE(0, Acur, Bcur, {                                                     \
            if (DOSTAGE) {                                                         \
                async16((Aoth) + wv * 512,        gA + (size_t)(kt1) * 64);        \
                async16((Aoth) + 4096 + wv * 512, gA + 65536 + (size_t)(kt1) * 64);\
            }                                                                      \
        });                                                                        \
        __builtin_amdgcn_s_barrier();                                              \
        PHASE(1, Acur, Bcur, {                                                     \
            if (DOSTAGE) {                                                         \
                async16((Aoth) + 8192 + wv * 512,  gA + 131072 + (size_t)(kt1) * 64); \
                async16((Aoth) + 12288 + wv * 512, gA + 196608 + (size_t)(kt1) * 64); \
            }                                                                      \
        });                                                                        \
        __builtin_amdgcn_s_barrier();                                              \
        PHASE(2, Acur, Bcur, {                                                     \
            if (DOSTAGE) {                                                         \
                async16((Both) + wv * 512,        gB + (size_t)(kt1) * 64);        \
                async16((Both) + 4096 + wv * 512, gB + 65536 + (size_t)(kt1) * 64);\
            }                                                                      \
        });                                                                        \
        __builtin_amdgcn_s_barrier();                                              \
        PHASE(3, Acur, Bcur, {});                                                  \
        asm volatile("s_waitcnt vmcnt(0)" ::: "memory");                           \
        __builtin_amdgcn_s_barrier();                                              \
    } while (0)

    // prologue: stage tile 0 into buf0
    async16(A0v + wv * 512,          gA);
    async16(A0v + 4096 + wv * 512,   gA + 65536);
    async16(A0v + 8192 + wv * 512,   gA + 131072);
    async16(A0v + 12288 + wv * 512,  gA + 196608);
    async16(B0v + wv * 512,          gB);
    async16(B0v + 4096 + wv * 512,   gB + 65536);
    asm volatile("s_waitcnt vmcnt(0)" ::: "memory");
    __builtin_amdgcn_s_barrier();

    for (int kt = 0; kt < 14; kt += 2) {
        KTILE(A0v, B0v, A1v, B1v, kt + 1, true);
        KTILE(A1v, B1v, A0v, B0v, kt + 2, true);
    }
    KTILE(A0v, B0v, A1v, B1v, 15, true);    // tile 14, stage 15
    KTILE(A1v, B1v, A0v, B0v, 0, false);    // tile 15, no stage

    // epilogue: bias + activation mixture
    #pragma unroll
    for (int ni = 0; ni < 4; ++ni) {
        int col = bcol + wcn + ni * 16 + fr;
        #pragma unroll
        for (int mi = 0; mi < 4; ++mi) {
            int row = brow + wr + mi * 16 + (lane >> 4) * 4;
            #pragma unroll
            for (int r = 0; r < 4; ++r) {
                float v = acc[mi][ni][r] + bias[ni];
                out[(size_t)(row + r) * 1024 + col] = as0 * v + as1 * fmaxf(v, 0.f);
            }
        }
    }
#undef PHASE
#undef KTILE
}

// ---------------- fallback (only if workspace too small): naive fp32 ----------------
__global__ __launch_bounds__(256) void naive_kernel(const float* __restrict__ x,
                                                    const float* __restrict__ Wseed,
                                                    const float* __restrict__ bseed,
                                                    const float* __restrict__ Wsig,
                                                    const float* __restrict__ bsig,
                                                    const float* __restrict__ asig,
                                                    float* __restrict__ out) {
    int idx = blockIdx.x * 256 + threadIdx.x;
    int b = idx >> 10, o = idx & 1023;
    float ws0, ws1, bs0, bs1, as0, as1;
    softmax2(Wsig, ws0, ws1);
    softmax2(bsig, bs0, bs1);
    softmax2(asig, as0, as1);
    float s = 0.f;
    const float* xr = x + (size_t)b * 1024;
    for (int k = 0; k < 1024; ++k) {
        float wc = ws0 * Wseed[((size_t)k << 10) + o] + ws1 * toep_val(Wseed, k, o);
        s += xr[k] * wc;
    }
    float v = s + bs0 * bseed[o];
    out[idx] = as0 * v + as1 * fmaxf(v, 0.f);
}

extern "C" void kernel_launch(void* const* d_in, const int* in_sizes, int n_in,
                              void* d_out, int out_size, void* d_ws, size_t ws_size,
                              hipStream_t stream) {
    const float* x     = (const float*)d_in[0];
    const float* Wseed = (const float*)d_in[1];
    const float* bseed = (const float*)d_in[2];
    const float* Wsig  = (const float*)d_in[3];
    const float* bsig  = (const float*)d_in[4];
    const float* Asig  = (const float*)d_in[5];
    float* out = (float*)d_out;

    const size_t need = (2u << 20) + (16u << 20) + 1024;
    if (ws_size < need) {
        naive_kernel<<<dim3(8192 * 1024 / 256), dim3(256), 0, stream>>>(
            x, Wseed, bseed, Wsig, bsig, Asig, out);
        return;
    }

    ushort_t* Wt = (ushort_t*)d_ws;                         // 2 MB: W_core^T bf16 [1024][1024]
    ushort_t* Xb = (ushort_t*)((char*)d_ws + (2u << 20));   // 16 MB: x bf16 [8192][1024]

    prep_kernel<<<dim3(4096 + 256), dim3(256), 0, stream>>>(x, Wseed, Wsig, Xb, Wt);
    gemm_kernel<<<dim3(256), dim3(512), 0, stream>>>(Xb, Wt, bseed, bsig, Asig, out);
}